// Round 3
// baseline (483.226 us; speedup 1.0000x reference)
//
#include <hip/hip_runtime.h>
#include <math.h>

// Problem: heatmaps [N=16, J=24, D=64, H=64, W=64] fp32.
// Softmax over flattened D*H*W per (n,j) slab, then soft-argmax marginals:
// out[n,j,0..2] = (E[w], E[h], E[d]) / 64 - 0.5
//
// Single-pass online softmax fused with weighted coordinate sums.
// HBM-bound: 402.7 MB read once -> ~62 us floor at 6.45 TB/s.
// R3: 4 float4 in flight per thread (deeper MLP), closed-form coords:
//     w0=(4t)&63 const; h_q=(t>>4)+16q const per pack; d=chunk*8+it.

#define SLABS       384        // 16*24
#define SLAB_ELEMS  262144     // 64^3
#define CHUNKS      8          // blocks per slab
#define BLOCK       256
#define CHUNK_ELEMS (SLAB_ELEMS / CHUNKS)            // 32768 elems
#define ITERS       (CHUNK_ELEMS / (BLOCK * 16))     // 8 iters x 16 elem/thread

typedef float f32x4 __attribute__((ext_vector_type(4)));

__device__ __forceinline__ float fast_exp2(float x) {
#if __has_builtin(__builtin_amdgcn_exp2f)
    return __builtin_amdgcn_exp2f(x);
#else
    return exp2f(x);
#endif
}

// Combine two online-softmax tuples (log2-domain max ml, sums S, Sx, Sy, Sz).
__device__ __forceinline__ void combine(float& ml, float& S, float& Sx, float& Sy, float& Sz,
                                        float oml, float oS, float oSx, float oSy, float oSz) {
    float nml = fmaxf(ml, oml);
    float sa = fast_exp2(ml - nml);
    float sb = fast_exp2(oml - nml);
    S  = S * sa  + oS * sb;
    Sx = Sx * sa + oSx * sb;
    Sy = Sy * sa + oSy * sb;
    Sz = Sz * sa + oSz * sb;
    ml = nml;
}

__device__ __forceinline__ float max4(f32x4 v) {
    return fmaxf(fmaxf(v.x, v.y), fmaxf(v.z, v.w));
}

// exp2 all 4 lanes of v*LOG2E - ml; accumulate pack sum and within-pack x-weight.
__device__ __forceinline__ void pack_exp(f32x4 v, float ml, float& s, float& x) {
    const float LOG2E = 1.4426950408889634f;
    const float e0 = fast_exp2(__builtin_fmaf(v.x, LOG2E, -ml));
    const float e1 = fast_exp2(__builtin_fmaf(v.y, LOG2E, -ml));
    const float e2 = fast_exp2(__builtin_fmaf(v.z, LOG2E, -ml));
    const float e3 = fast_exp2(__builtin_fmaf(v.w, LOG2E, -ml));
    s = (e0 + e1) + (e2 + e3);
    x = __builtin_fmaf(3.f, e3, __builtin_fmaf(2.f, e2, e1));
}

__global__ __launch_bounds__(BLOCK) void jir_partial_kernel(const float* __restrict__ in,
                                                            float* __restrict__ ws) {
    const int slab  = blockIdx.x / CHUNKS;
    const int chunk = blockIdx.x % CHUNKS;
    const f32x4* __restrict__ B =
        (const f32x4*)(in + (size_t)slab * SLAB_ELEMS + (size_t)chunk * CHUNK_ELEMS);
    const int tid = threadIdx.x;

    const float LOG2E = 1.4426950408889634f;

    // Element flat idx within slab = chunk*32768 + (it*1024 + q*256 + tid)*4, q=0..3:
    //   w0  = (4*tid) & 63                -- constant per thread
    //   h_q = (tid>>4) + 16*q             -- constant per thread & pack (it-independent)
    //   d   = chunk*8 + it                -- same for all 4 packs
    const float w0f   = (float)((4 * tid) & 63);
    const float h0f   = (float)(tid >> 4);
    const float dbase = (float)(chunk * 8);

    float ml = -INFINITY;   // running max, pre-scaled by log2(e)
    float S = 0.f, Sx = 0.f, Sy = 0.f, Sz = 0.f;

    f32x4 c0 = __builtin_nontemporal_load(B + tid);
    f32x4 c1 = __builtin_nontemporal_load(B + tid + 256);
    f32x4 c2 = __builtin_nontemporal_load(B + tid + 512);
    f32x4 c3 = __builtin_nontemporal_load(B + tid + 768);

#pragma unroll
    for (int it = 0; it < ITERS; ++it) {
        f32x4 n0, n1, n2, n3;
        if (it < ITERS - 1) {
            const int nb = (it + 1) * 1024 + tid;
            n0 = __builtin_nontemporal_load(B + nb);
            n1 = __builtin_nontemporal_load(B + nb + 256);
            n2 = __builtin_nontemporal_load(B + nb + 512);
            n3 = __builtin_nontemporal_load(B + nb + 768);
        }

        const float ddf = dbase + (float)it;

        const float nml = fmaxf(fmaxf(max4(c0), max4(c1)),
                                fmaxf(max4(c2), max4(c3))) * LOG2E;
        if (nml > ml) {                         // some lane hits this most iters; body is cheap
            const float scale = fast_exp2(ml - nml);  // ml=-inf first -> 0
            S *= scale; Sx *= scale; Sy *= scale; Sz *= scale;
            ml = nml;
        }

        float s0, s1, s2, s3, x0, x1, x2, x3;
        pack_exp(c0, ml, s0, x0);
        pack_exp(c1, ml, s1, x1);
        pack_exp(c2, ml, s2, x2);
        pack_exp(c3, ml, s3, x3);

        const float s_tot = (s0 + s1) + (s2 + s3);
        const float xsum  = (x0 + x1) + (x2 + x3);
        // Sy: sum_q s_q*(h0+16q) = s_tot*h0 + 16*(s1 + 2*s2 + 3*s3)
        const float hq    = __builtin_fmaf(3.f, s3, __builtin_fmaf(2.f, s2, s1));

        S  += s_tot;
        Sx  = __builtin_fmaf(s_tot, w0f, Sx + xsum);
        Sy  = __builtin_fmaf(s_tot, h0f, __builtin_fmaf(16.f, hq, Sy));
        Sz  = __builtin_fmaf(s_tot, ddf, Sz);

        c0 = n0; c1 = n1; c2 = n2; c3 = n3;
    }

    // Wave-level butterfly reduction over 64 lanes.
#pragma unroll
    for (int off = 1; off < 64; off <<= 1) {
        float oml = __shfl_xor(ml, off, 64);
        float oS  = __shfl_xor(S,  off, 64);
        float oSx = __shfl_xor(Sx, off, 64);
        float oSy = __shfl_xor(Sy, off, 64);
        float oSz = __shfl_xor(Sz, off, 64);
        combine(ml, S, Sx, Sy, Sz, oml, oS, oSx, oSy, oSz);
    }

    // Cross-wave combine through LDS (4 waves per block).
    __shared__ float red[4][5];
    const int wave = tid >> 6;
    const int lane = tid & 63;
    if (lane == 0) {
        red[wave][0] = ml; red[wave][1] = S; red[wave][2] = Sx;
        red[wave][3] = Sy; red[wave][4] = Sz;
    }
    __syncthreads();
    if (tid == 0) {
        float fml = red[0][0], fS = red[0][1], fSx = red[0][2], fSy = red[0][3], fSz = red[0][4];
#pragma unroll
        for (int wv = 1; wv < 4; ++wv) {
            combine(fml, fS, fSx, fSy, fSz,
                    red[wv][0], red[wv][1], red[wv][2], red[wv][3], red[wv][4]);
        }
        float* o = ws + (size_t)blockIdx.x * 5;
        o[0] = fml; o[1] = fS; o[2] = fSx; o[3] = fSy; o[4] = fSz;
    }
}

__global__ __launch_bounds__(64) void jir_finalize_kernel(const float* __restrict__ ws,
                                                          float* __restrict__ out) {
    const int slab = blockIdx.x * 64 + threadIdx.x;
    if (slab >= SLABS) return;

    const float* p0 = ws + (size_t)slab * CHUNKS * 5;
    float ml = p0[0], S = p0[1], Sx = p0[2], Sy = p0[3], Sz = p0[4];
#pragma unroll
    for (int c = 1; c < CHUNKS; ++c) {
        const float* p = p0 + c * 5;
        combine(ml, S, Sx, Sy, Sz, p[0], p[1], p[2], p[3], p[4]);
    }
    const float inv = 1.0f / S;
    out[slab * 3 + 0] = (Sx * inv) * (1.0f / 64.0f) - 0.5f;
    out[slab * 3 + 1] = (Sy * inv) * (1.0f / 64.0f) - 0.5f;
    out[slab * 3 + 2] = (Sz * inv) * (1.0f / 64.0f) - 0.5f;
}

extern "C" void kernel_launch(void* const* d_in, const int* in_sizes, int n_in,
                              void* d_out, int out_size, void* d_ws, size_t ws_size,
                              hipStream_t stream) {
    const float* heatmaps = (const float*)d_in[0];
    float* out = (float*)d_out;
    float* ws = (float*)d_ws;   // SLABS*CHUNKS*5 floats = 61.4 KB

    jir_partial_kernel<<<SLABS * CHUNKS, BLOCK, 0, stream>>>(heatmaps, ws);
    jir_finalize_kernel<<<(SLABS + 63) / 64, 64, 0, stream>>>(ws, out);
}